// Round 2
// baseline (2839.839 us; speedup 1.0000x reference)
//
#include <hip/hip_runtime.h>
#include <hip/hip_bf16.h>

#define HID 128
#define TILE 64
#define TPB 256

__device__ __forceinline__ float bf2f(unsigned short u) {
    return __uint_as_float(((unsigned int)u) << 16);
}
__device__ __forceinline__ unsigned short f2bf(float f) {
    unsigned int u = __float_as_uint(f);
    unsigned int r = (u + 0x7FFFu + ((u >> 16) & 1u)) >> 16;  // RNE
    return (unsigned short)r;
}
__device__ __forceinline__ float silu(float x) {
    return x / (1.0f + __expf(-x));
}
// LDS layout for h tiles: [k][a], bf16, XOR swizzle on a (4-element granules)
__device__ __forceinline__ int hidx(int k, int a) {
    return k * TILE + (a ^ ((k & 15) << 2));
}

__global__ __launch_bounds__(TPB, 2) void mlp_kernel(
    const float* __restrict__ pos, const int* __restrict__ anum,
    const int* __restrict__ batch,
    const float* __restrict__ W_in, const float* __restrict__ b_in,
    const float* __restrict__ W_h, const float* __restrict__ b_h,
    const float* __restrict__ W_e, const float* __restrict__ b_e,
    float* __restrict__ out_energies,   // d_out base (energies at offset 0)
    float* __restrict__ ws_h3sum,
    int nAtoms)
{
    __shared__ unsigned short smem[32768];      // exactly 64 KB
    unsigned short* Wl = smem;                  // [128*128] bf16 (one layer)
    unsigned short* hA = smem + 16384;          // [128][64] bf16
    unsigned short* hB = smem + 24576;          // [128][64] bf16
    float* red = (float*)(smem + 24576);        // overlaps hB (used when hB dead)

    const int t = threadIdx.x;
    const int j = t & 127;   // feature
    const int s = t >> 7;    // atom slab 0/1

    // hoisted per-thread constants
    float win0 = W_in[0 * HID + j];
    float win1 = W_in[1 * HID + j];
    float win2 = W_in[2 * HID + j];
    float win3 = W_in[3 * HID + j];
    const float bin = b_in[j];
    const float bh0 = b_h[j];
    const float bh1 = b_h[HID + j];

    float sacc = 0.0f;  // running sum of h3[j] over this thread's atoms

    const int nTiles = (nAtoms + TILE - 1) / TILE;
    for (int tile = blockIdx.x; tile < nTiles; tile += gridDim.x) {
        const int base = tile * TILE;
        __syncthreads();  // protect previous tile's LDS reads

        // ---- stage W layer 0 (bf16) + compute h1 -> hA ----
        for (int p = 0; p < HID * HID; p += TPB)
            Wl[p + t] = f2bf(W_h[p + t]);

        for (int a0 = 0; a0 < 32; a0 += 4) {
            const int a = s * 32 + a0;
            float x[4];
            #pragma unroll
            for (int i = 0; i < 4; ++i) {
                int ga = base + a + i;
                if (ga >= nAtoms) ga = nAtoms - 1;  // clamp (harmless, e zeroed later)
                const float px = pos[ga * 3 + 0];
                const float py = pos[ga * 3 + 1];
                const float pz = pos[ga * 3 + 2];
                const float z  = (float)anum[ga];
                float v = fmaf(win0, px, fmaf(win1, py, fmaf(win2, pz, fmaf(win3, z, bin))));
                x[i] = silu(v);
            }
            ushort4 w4;
            w4.x = f2bf(x[0]); w4.y = f2bf(x[1]); w4.z = f2bf(x[2]); w4.w = f2bf(x[3]);
            *reinterpret_cast<ushort4*>(&hA[hidx(j, a)]) = w4;
        }
        __syncthreads();

        // ---- layer 0: hA -> hB ----
        for (int a0 = 0; a0 < 32; a0 += 4) {
            const int a = s * 32 + a0;
            float x0 = bh0, x1 = bh0, x2 = bh0, x3 = bh0;
            #pragma unroll 4
            for (int k = 0; k < HID; ++k) {
                const float w = bf2f(Wl[k * HID + j]);
                const ushort4 hv = *reinterpret_cast<const ushort4*>(&hA[hidx(k, a)]);
                x0 = fmaf(bf2f(hv.x), w, x0);
                x1 = fmaf(bf2f(hv.y), w, x1);
                x2 = fmaf(bf2f(hv.z), w, x2);
                x3 = fmaf(bf2f(hv.w), w, x3);
            }
            ushort4 w4;
            w4.x = f2bf(silu(x0)); w4.y = f2bf(silu(x1));
            w4.z = f2bf(silu(x2)); w4.w = f2bf(silu(x3));
            *reinterpret_cast<ushort4*>(&hB[hidx(j, a)]) = w4;
        }
        __syncthreads();

        // ---- stage W layer 1 ----
        for (int p = 0; p < HID * HID; p += TPB)
            Wl[p + t] = f2bf(W_h[HID * HID + p + t]);
        __syncthreads();

        // ---- layer 1: hB -> hA (h3), accumulate stress sum ----
        for (int a0 = 0; a0 < 32; a0 += 4) {
            const int a = s * 32 + a0;
            float x0 = bh1, x1 = bh1, x2 = bh1, x3 = bh1;
            #pragma unroll 4
            for (int k = 0; k < HID; ++k) {
                const float w = bf2f(Wl[k * HID + j]);
                const ushort4 hv = *reinterpret_cast<const ushort4*>(&hB[hidx(k, a)]);
                x0 = fmaf(bf2f(hv.x), w, x0);
                x1 = fmaf(bf2f(hv.y), w, x1);
                x2 = fmaf(bf2f(hv.z), w, x2);
                x3 = fmaf(bf2f(hv.w), w, x3);
            }
            x0 = silu(x0); x1 = silu(x1); x2 = silu(x2); x3 = silu(x3);
            sacc += x0 + x1 + x2 + x3;
            ushort4 w4;
            w4.x = f2bf(x0); w4.y = f2bf(x1); w4.z = f2bf(x2); w4.w = f2bf(x3);
            *reinterpret_cast<ushort4*>(&hA[hidx(j, a)]) = w4;
        }
        __syncthreads();

        // ---- epilogue: e = h3 @ W_e + b_e, partials over 4 k-chunks ----
        {
            const int a = t & 63;
            const int c = t >> 6;
            float p = 0.f;
            #pragma unroll 4
            for (int kk = 0; kk < 32; ++kk) {
                const int k = c * 32 + kk;
                p = fmaf(bf2f(hA[hidx(k, a)]), W_e[k], p);
            }
            red[c * 64 + a] = p;   // red aliases hB (dead)
        }
        __syncthreads();

        if (t < 64) {
            const int a = t;
            const int ga = base + a;
            float e = red[a] + red[64 + a] + red[128 + a] + red[192 + a] + b_e[0];
            int key;
            if (ga < nAtoms) {
                key = batch[ga];
            } else {
                key = -1; e = 0.f;
            }
            // segmented suffix-sum over sorted keys (wave 0, 64 lanes)
            #pragma unroll
            for (int d = 1; d < 64; d <<= 1) {
                const float eo = __shfl_down(e, d);
                const int   ko = __shfl_down(key, d);
                const bool valid = ((t + d) < 64) && (ko == key);
                e += valid ? eo : 0.f;
            }
            const int kprev = __shfl_up(key, 1);
            const bool head = (t == 0) || (kprev != key);
            if (head && key >= 0) atomicAdd(&out_energies[key], e);
        }
    }

    // ---- stress partial: reduce sacc across the two slabs, one atomic per feat ----
    __syncthreads();
    red[t] = sacc;
    __syncthreads();
    if (t < HID) atomicAdd(&ws_h3sum[t], red[t] + red[t + HID]);
}

__global__ void stress_kernel(const float* __restrict__ ws_h3sum,
                              const float* __restrict__ W_s,
                              const float* __restrict__ b_s,
                              float* __restrict__ out_stress, float invN)
{
    const int m = threadIdx.x;
    if (m < 6) {
        float acc = 0.f;
        for (int k = 0; k < HID; ++k)
            acc = fmaf(ws_h3sum[k], W_s[k * 6 + m], acc);
        out_stress[m] = fmaf(acc, invN, b_s[m]) ;
    }
}

extern "C" void kernel_launch(void* const* d_in, const int* in_sizes, int n_in,
                              void* d_out, int out_size, void* d_ws, size_t ws_size,
                              hipStream_t stream) {
    const float* pos  = (const float*)d_in[0];
    const int*   anum = (const int*)d_in[1];
    const int*   batch= (const int*)d_in[2];
    const float* W_in = (const float*)d_in[3];
    const float* b_in = (const float*)d_in[4];
    const float* W_h  = (const float*)d_in[5];
    const float* b_h  = (const float*)d_in[6];
    const float* W_e  = (const float*)d_in[7];
    const float* b_e  = (const float*)d_in[8];
    const float* W_s  = (const float*)d_in[9];
    const float* b_s  = (const float*)d_in[10];

    float* out = (float*)d_out;
    const int nAtoms = in_sizes[2];                 // batch[] length == N
    const int nStruct = out_size - 3 * nAtoms - 6;  // energies | forces | stress
    float* ws_h3 = (float*)d_ws;

    // zero energies + forces (+stress slots) and the h3-sum scratch
    hipMemsetAsync(d_out, 0, (size_t)out_size * sizeof(float), stream);
    hipMemsetAsync(d_ws, 0, HID * sizeof(float), stream);

    mlp_kernel<<<2048, TPB, 0, stream>>>(pos, anum, batch, W_in, b_in, W_h, b_h,
                                         W_e, b_e, out, ws_h3, nAtoms);
    stress_kernel<<<1, 64, 0, stream>>>(ws_h3, W_s, b_s,
                                        out + (size_t)nStruct + 3 * (size_t)nAtoms,
                                        1.0f / (float)nAtoms);
}

// Round 4
// 646.379 us; speedup vs baseline: 4.3935x; 4.3935x over previous
//
#include <hip/hip_runtime.h>

#define HID 128
#define TPB 256
#define NBLOCKS 768   // 256 CU x 3 blocks/CU (42KB LDS, ~150 VGPR -> 3/SIMD)

typedef __attribute__((ext_vector_type(8))) short short8v;   // 8 bf16 = 4 VGPR (MFMA A/B frag)
typedef __attribute__((ext_vector_type(16))) float f32x16;   // MFMA C/D frag

__device__ __forceinline__ float bf2f(unsigned short u) {
    return __uint_as_float(((unsigned int)u) << 16);
}
__device__ __forceinline__ unsigned short f2bf(float f) {
    unsigned int u = __float_as_uint(f);
    return (unsigned short)((u + 0x7FFFu + ((u >> 16) & 1u)) >> 16);  // RNE
}
__device__ __forceinline__ float silu(float x) {
    return x / (1.0f + __expf(-x));
}
// h tiles in LDS: [64 atoms][128 feats] bf16, XOR swizzle (16B granule over 8 rows)
// index in shorts. Keeps 16B (b128) and 8B (ushort4) accesses aligned.
__device__ __forceinline__ int swz(int m, int k) {
    return (m * HID + k) ^ ((m & 7) << 3);
}

__global__ __launch_bounds__(TPB, 3) void mlp_kernel(
    const float* __restrict__ pos, const int* __restrict__ anum,
    const int* __restrict__ batch,
    const float* __restrict__ W_in, const float* __restrict__ b_in,
    const float* __restrict__ W_h, const float* __restrict__ b_h,
    const float* __restrict__ W_e, const float* __restrict__ b_e,
    const float* __restrict__ W_s,
    float* __restrict__ out_energies,   // d_out base (energies at offset 0)
    float* __restrict__ ws6,            // 6 stress partial sums
    int nAtoms)
{
    __shared__ unsigned short h1[64 * HID];   // 16 KB
    __shared__ unsigned short h2[64 * HID];   // 16 KB
    __shared__ float featsL[64][4];           // 1 KB
    __shared__ float bh0L[HID], bh1L[HID], WeL[HID];
    __shared__ float WsL[HID][8];             // 4 KB (rows 32B-aligned)
    __shared__ float ered[4 * 64];            // 1 KB

    const int t    = threadIdx.x;
    const int lane = t & 63;
    const int w    = t >> 6;          // wave 0..3, owns feature block Fw..Fw+31
    const int hi   = lane >> 5;       // lane half (selects k-slice of fragments)
    const int lm   = lane & 31;       // MFMA row/col index
    const int Fw   = 32 * w;

    // ---- stage small constant tables (once per block) ----
    if (t < HID) {
        bh0L[t] = b_h[t];
        bh1L[t] = b_h[HID + t];
        WeL[t]  = W_e[t];
        #pragma unroll
        for (int c = 0; c < 6; ++c) WsL[t][c] = W_s[t * 6 + c];
    }

    // ---- per-thread h1 (input layer) weights: feature j ----
    const int j    = t & 127;
    const int slab = t >> 7;          // atoms [32*slab, 32*slab+32)
    const float wi0 = W_in[0 * HID + j], wi1 = W_in[1 * HID + j];
    const float wi2 = W_in[2 * HID + j], wi3 = W_in[3 * HID + j];
    const float bin = b_in[j];
    const float be  = b_e[0];

    // ---- preload W^T A-fragments for both hidden layers (registers, 64 VGPR) ----
    // A-frag (32x32x16): lane holds A[row = lm][k = 16s + 8*hi + i], i=0..7
    // A = W^T : A[f][k] = W_h[layer][k][f]
    short8v A0[8], A1[8];
    {
        const int fc = Fw + lm;
        for (int s = 0; s < 8; ++s) {
            short8v a0, a1;
            #pragma unroll
            for (int i = 0; i < 8; ++i) {
                const int k = 16 * s + 8 * hi + i;
                a0[i] = (short)f2bf(W_h[k * HID + fc]);
                a1[i] = (short)f2bf(W_h[HID * HID + k * HID + fc]);
            }
            A0[s] = a0; A1[s] = a1;
        }
    }

    float sacc[6] = {0.f, 0.f, 0.f, 0.f, 0.f, 0.f};

    const int nTiles = (nAtoms + 63) >> 6;
    for (int tile = blockIdx.x; tile < nTiles; tile += gridDim.x) {
        const int base = tile << 6;
        __syncthreads();   // protect prev-tile LDS readers before rewrite

        // ---- stage atom features [64][4] ----
        if (t < 192) {
            int idx = base * 3 + t;
            const int gmax = nAtoms * 3 - 1;
            if (idx > gmax) idx = gmax;
            featsL[t / 3][t % 3] = pos[idx];
        } else if (t < 256) {
            const int a = t - 192;
            int ga = base + a; if (ga >= nAtoms) ga = nAtoms - 1;
            featsL[a][3] = (float)anum[ga];
        }
        __syncthreads();

        // ---- input layer: h1[a][j] = silu(feats @ W_in + b_in) ----
        for (int ai = 0; ai < 32; ++ai) {
            const int a = 32 * slab + ai;
            const float4 ft = *reinterpret_cast<const float4*>(&featsL[a][0]);
            const float z = fmaf(wi0, ft.x, fmaf(wi1, ft.y,
                            fmaf(wi2, ft.z, fmaf(wi3, ft.w, bin))));
            h1[swz(a, j)] = f2bf(silu(z));
        }
        __syncthreads();

        // ---- layer 0 MFMA: z2[f][m] = W0^T · h1^T + b0 ----
        f32x16 acc0, acc1;
        #pragma unroll
        for (int r = 0; r < 16; ++r) {
            const float b = bh0L[Fw + (r & 3) + 8 * (r >> 2) + 4 * hi];
            acc0[r] = b; acc1[r] = b;
        }
        #pragma unroll
        for (int s = 0; s < 8; ++s) {
            const int k0 = 16 * s + 8 * hi;
            const short8v Ba = *reinterpret_cast<const short8v*>(&h1[swz(lm,      k0)]);
            const short8v Bb = *reinterpret_cast<const short8v*>(&h1[swz(32 + lm, k0)]);
            acc0 = __builtin_amdgcn_mfma_f32_32x32x16_bf16(A0[s], Ba, acc0, 0, 0, 0);
            acc1 = __builtin_amdgcn_mfma_f32_32x32x16_bf16(A0[s], Bb, acc1, 0, 0, 0);
        }
        // silu -> bf16 -> h2 (C/D reg quads are 4 consecutive f rows -> ushort4 stores)
        #pragma unroll
        for (int g = 0; g < 4; ++g) {
            const int f0 = Fw + 8 * g + 4 * hi;
            ushort4 pa, pb;
            pa.x = f2bf(silu(acc0[4*g+0])); pa.y = f2bf(silu(acc0[4*g+1]));
            pa.z = f2bf(silu(acc0[4*g+2])); pa.w = f2bf(silu(acc0[4*g+3]));
            pb.x = f2bf(silu(acc1[4*g+0])); pb.y = f2bf(silu(acc1[4*g+1]));
            pb.z = f2bf(silu(acc1[4*g+2])); pb.w = f2bf(silu(acc1[4*g+3]));
            *reinterpret_cast<ushort4*>(&h2[swz(lm,      f0)]) = pa;
            *reinterpret_cast<ushort4*>(&h2[swz(32 + lm, f0)]) = pb;
        }
        __syncthreads();

        // ---- layer 1 MFMA: z3[f][m] = W1^T · h2^T + b1 ----
        #pragma unroll
        for (int r = 0; r < 16; ++r) {
            const float b = bh1L[Fw + (r & 3) + 8 * (r >> 2) + 4 * hi];
            acc0[r] = b; acc1[r] = b;
        }
        #pragma unroll
        for (int s = 0; s < 8; ++s) {
            const int k0 = 16 * s + 8 * hi;
            const short8v Ba = *reinterpret_cast<const short8v*>(&h2[swz(lm,      k0)]);
            const short8v Bb = *reinterpret_cast<const short8v*>(&h2[swz(32 + lm, k0)]);
            acc0 = __builtin_amdgcn_mfma_f32_32x32x16_bf16(A1[s], Ba, acc0, 0, 0, 0);
            acc1 = __builtin_amdgcn_mfma_f32_32x32x16_bf16(A1[s], Bb, acc1, 0, 0, 0);
        }

        // ---- epilogue: h3 = silu(z3); energies dot W_e; stress dot W_s ----
        const bool v0 = (base + lm)      < nAtoms;
        const bool v1 = (base + 32 + lm) < nAtoms;
        float e0 = 0.f, e1 = 0.f;
        #pragma unroll
        for (int r = 0; r < 16; ++r) {
            const int f = Fw + (r & 3) + 8 * (r >> 2) + 4 * hi;
            const float h3a = silu(acc0[r]);
            const float h3b = silu(acc1[r]);
            const float we = WeL[f];
            e0 = fmaf(h3a, we, e0);
            e1 = fmaf(h3b, we, e1);
            const float hs = (v0 ? h3a : 0.f) + (v1 ? h3b : 0.f);
            #pragma unroll
            for (int c = 0; c < 6; ++c) sacc[c] = fmaf(hs, WsL[f][c], sacc[c]);
        }
        // combine lane halves: each lane then holds full e for its atom column
        e0 += __shfl_xor(e0, 32);
        e1 += __shfl_xor(e1, 32);
        const float ev = (lane < 32) ? e0 : e1;   // lane l <-> atom base+l
        ered[w * 64 + lane] = ev;
        __syncthreads();

        // ---- wave 0: sum feature slices, add b_e, segmented-scan, atomic ----
        if (w == 0) {
            float e = ered[lane] + ered[64 + lane] + ered[128 + lane] + ered[192 + lane] + be;
            const int ga = base + lane;
            int key = (ga < nAtoms) ? batch[ga] : -1;
            if (key < 0) e = 0.f;
            #pragma unroll
            for (int d = 1; d < 64; d <<= 1) {
                const float eo = __shfl_down(e, d);
                const int   ko = __shfl_down(key, d);
                const bool valid = ((lane + d) < 64) && (ko == key);
                e += valid ? eo : 0.f;
            }
            const int kprev = __shfl_up(key, 1);
            const bool head = (lane == 0) || (kprev != key);
            if (head && key >= 0) atomicAdd(&out_energies[key], e);
        }
    }

    // ---- stress: reduce 6 per-lane partials across wave, one atomic each ----
    #pragma unroll
    for (int c = 0; c < 6; ++c) {
        float v = sacc[c];
        #pragma unroll
        for (int d = 1; d < 64; d <<= 1) v += __shfl_xor(v, d);
        if (lane == 0) atomicAdd(&ws6[c], v);
    }
}

__global__ void stress_kernel(const float* __restrict__ ws6,
                              const float* __restrict__ b_s,
                              float* __restrict__ out_stress, float invN)
{
    const int c = threadIdx.x;
    if (c < 6) out_stress[c] = fmaf(ws6[c], invN, b_s[c]);
}

extern "C" void kernel_launch(void* const* d_in, const int* in_sizes, int n_in,
                              void* d_out, int out_size, void* d_ws, size_t ws_size,
                              hipStream_t stream) {
    const float* pos  = (const float*)d_in[0];
    const int*   anum = (const int*)d_in[1];
    const int*   batch= (const int*)d_in[2];
    const float* W_in = (const float*)d_in[3];
    const float* b_in = (const float*)d_in[4];
    const float* W_h  = (const float*)d_in[5];
    const float* b_h  = (const float*)d_in[6];
    const float* W_e  = (const float*)d_in[7];
    const float* b_e  = (const float*)d_in[8];
    const float* W_s  = (const float*)d_in[9];
    const float* b_s  = (const float*)d_in[10];

    float* out = (float*)d_out;
    const int nAtoms  = in_sizes[2];                 // batch[] length == N
    const int nStruct = out_size - 3 * nAtoms - 6;   // energies | forces | stress
    float* ws6 = (float*)d_ws;

    hipMemsetAsync(d_out, 0, (size_t)out_size * sizeof(float), stream);
    hipMemsetAsync(d_ws, 0, 32, stream);

    mlp_kernel<<<NBLOCKS, TPB, 0, stream>>>(pos, anum, batch, W_in, b_in, W_h, b_h,
                                            W_e, b_e, W_s, out, ws6, nAtoms);
    stress_kernel<<<1, 64, 0, stream>>>(ws6, b_s,
                                        out + (size_t)nStruct + 3 * (size_t)nAtoms,
                                        1.0f / (float)nAtoms);
}

// Round 6
// 640.286 us; speedup vs baseline: 4.4353x; 1.0095x over previous
//
#include <hip/hip_runtime.h>

#define HID 128
#define TPB 256
#define NBLOCKS 768   // 256 CU x 3 blocks/CU (40KB LDS, ~150 VGPR -> 3 waves/EU)

typedef __attribute__((ext_vector_type(8))) short short8v;   // 8 bf16 = 4 VGPR (MFMA A/B frag)
typedef __attribute__((ext_vector_type(16))) float f32x16;   // MFMA C/D frag

__device__ __forceinline__ float bf2f(unsigned short u) {
    return __uint_as_float(((unsigned int)u) << 16);
}
__device__ __forceinline__ unsigned short f2bf(float f) {
    unsigned int u = __float_as_uint(f);
    return (unsigned short)((u + 0x7FFFu + ((u >> 16) & 1u)) >> 16);  // RNE
}
__device__ __forceinline__ float silu(float x) {
    return x / (1.0f + __expf(-x));
}
// h tiles in LDS: [64 atoms][128 feats] bf16, XOR swizzle: 16B granule index
// (bits 3..6 of short-index) XORed with row&15 -> b128 column reads spread
// across 16 granule slots (was 8 -> 4-way conflict; now ~2-way = free).
__device__ __forceinline__ int swz(int m, int k) {
    return (m * HID + k) ^ ((m & 15) << 3);
}

__global__ __launch_bounds__(TPB, 3) void mlp_kernel(
    const float* __restrict__ pos, const int* __restrict__ anum,
    const int* __restrict__ batch,
    const float* __restrict__ W_in, const float* __restrict__ b_in,
    const float* __restrict__ W_h, const float* __restrict__ b_h,
    const float* __restrict__ W_e, const float* __restrict__ b_e,
    const float* __restrict__ W_s,
    float* __restrict__ out_energies,   // d_out base (energies at offset 0)
    float* __restrict__ ws6,            // 6 stress partial sums
    int nAtoms)
{
    __shared__ unsigned short h1[64 * HID];   // 16 KB
    __shared__ unsigned short h2[64 * HID];   // 16 KB
    __shared__ float featsL[64][4];           // 1 KB
    __shared__ float bh0L[HID], bh1L[HID], WeL[HID];
    __shared__ float WsL[HID][8];             // 4 KB (rows 32B-aligned)
    __shared__ float ered[4 * 64];            // 1 KB

    const int t    = threadIdx.x;
    const int lane = t & 63;
    const int w    = t >> 6;          // wave 0..3, owns feature block Fw..Fw+31
    const int hi   = lane >> 5;       // lane half (selects k-slice of fragments)
    const int lm   = lane & 31;       // MFMA row/col index
    const int Fw   = 32 * w;

    // ---- stage small constant tables (once per block) ----
    if (t < HID) {
        bh0L[t] = b_h[t];
        bh1L[t] = b_h[HID + t];
        WeL[t]  = W_e[t];
        #pragma unroll
        for (int c = 0; c < 6; ++c) WsL[t][c] = W_s[t * 6 + c];
    }

    // ---- per-thread h1 (input layer) weights: feature j ----
    const int j    = t & 127;
    const int slab = t >> 7;          // atoms [32*slab, 32*slab+32)
    const float wi0 = W_in[0 * HID + j], wi1 = W_in[1 * HID + j];
    const float wi2 = W_in[2 * HID + j], wi3 = W_in[3 * HID + j];
    const float bin = b_in[j];
    const float be  = b_e[0];

    // ---- preload W^T A-fragments for both hidden layers (registers, 64 VGPR) ----
    // A-frag (32x32x16): lane holds A[row = lm][k = 16s + 8*hi + i], i=0..7
    // A = W^T : A[f][k] = W_h[layer][k][f]
    // FULLY UNROLLED: every A0/A1 index must be compile-time constant or the
    // arrays land in scratch (R4: VGPR=84 + 633MB FETCH = spilled fragments).
    short8v A0[8], A1[8];
    {
        const int fc = Fw + lm;
        #pragma unroll
        for (int s = 0; s < 8; ++s) {
            short8v a0, a1;
            #pragma unroll
            for (int i = 0; i < 8; ++i) {
                const int k = 16 * s + 8 * hi + i;
                a0[i] = (short)f2bf(W_h[k * HID + fc]);
                a1[i] = (short)f2bf(W_h[HID * HID + k * HID + fc]);
            }
            A0[s] = a0; A1[s] = a1;
        }
    }

    float sacc[6] = {0.f, 0.f, 0.f, 0.f, 0.f, 0.f};

    const int nTiles = (nAtoms + 63) >> 6;
    for (int tile = blockIdx.x; tile < nTiles; tile += gridDim.x) {
        const int base = tile << 6;
        __syncthreads();   // protect prev-tile LDS readers before rewrite

        // ---- stage atom features [64][4] ----
        if (t < 192) {
            int idx = base * 3 + t;
            const int gmax = nAtoms * 3 - 1;
            if (idx > gmax) idx = gmax;
            featsL[t / 3][t % 3] = pos[idx];
        } else if (t < 256) {
            const int a = t - 192;
            int ga = base + a; if (ga >= nAtoms) ga = nAtoms - 1;
            featsL[a][3] = (float)anum[ga];
        }
        __syncthreads();

        // ---- input layer: h1[a][j] = silu(feats @ W_in + b_in) ----
        #pragma unroll 4
        for (int ai = 0; ai < 32; ++ai) {
            const int a = 32 * slab + ai;
            const float4 ft = *reinterpret_cast<const float4*>(&featsL[a][0]);
            const float z = fmaf(wi0, ft.x, fmaf(wi1, ft.y,
                            fmaf(wi2, ft.z, fmaf(wi3, ft.w, bin))));
            h1[swz(a, j)] = f2bf(silu(z));
        }
        __syncthreads();

        // ---- layer 0 MFMA: z2[f][m] = W0^T · h1^T + b0 ----
        f32x16 acc0, acc1;
        #pragma unroll
        for (int r = 0; r < 16; ++r) {
            const float b = bh0L[Fw + (r & 3) + 8 * (r >> 2) + 4 * hi];
            acc0[r] = b; acc1[r] = b;
        }
        #pragma unroll
        for (int s = 0; s < 8; ++s) {
            const int k0 = 16 * s + 8 * hi;
            const short8v Ba = *reinterpret_cast<const short8v*>(&h1[swz(lm,      k0)]);
            const short8v Bb = *reinterpret_cast<const short8v*>(&h1[swz(32 + lm, k0)]);
            acc0 = __builtin_amdgcn_mfma_f32_32x32x16_bf16(A0[s], Ba, acc0, 0, 0, 0);
            acc1 = __builtin_amdgcn_mfma_f32_32x32x16_bf16(A0[s], Bb, acc1, 0, 0, 0);
        }
        // silu -> bf16 -> h2 (C/D reg quads are 4 consecutive f rows -> ushort4 stores)
        #pragma unroll
        for (int g = 0; g < 4; ++g) {
            const int f0 = Fw + 8 * g + 4 * hi;
            ushort4 pa, pb;
            pa.x = f2bf(silu(acc0[4*g+0])); pa.y = f2bf(silu(acc0[4*g+1]));
            pa.z = f2bf(silu(acc0[4*g+2])); pa.w = f2bf(silu(acc0[4*g+3]));
            pb.x = f2bf(silu(acc1[4*g+0])); pb.y = f2bf(silu(acc1[4*g+1]));
            pb.z = f2bf(silu(acc1[4*g+2])); pb.w = f2bf(silu(acc1[4*g+3]));
            *reinterpret_cast<ushort4*>(&h2[swz(lm,      f0)]) = pa;
            *reinterpret_cast<ushort4*>(&h2[swz(32 + lm, f0)]) = pb;
        }
        __syncthreads();

        // ---- layer 1 MFMA: z3[f][m] = W1^T · h2^T + b1 ----
        #pragma unroll
        for (int r = 0; r < 16; ++r) {
            const float b = bh1L[Fw + (r & 3) + 8 * (r >> 2) + 4 * hi];
            acc0[r] = b; acc1[r] = b;
        }
        #pragma unroll
        for (int s = 0; s < 8; ++s) {
            const int k0 = 16 * s + 8 * hi;
            const short8v Ba = *reinterpret_cast<const short8v*>(&h2[swz(lm,      k0)]);
            const short8v Bb = *reinterpret_cast<const short8v*>(&h2[swz(32 + lm, k0)]);
            acc0 = __builtin_amdgcn_mfma_f32_32x32x16_bf16(A1[s], Ba, acc0, 0, 0, 0);
            acc1 = __builtin_amdgcn_mfma_f32_32x32x16_bf16(A1[s], Bb, acc1, 0, 0, 0);
        }

        // ---- epilogue: h3 = silu(z3); energies dot W_e; stress dot W_s ----
        const bool v0 = (base + lm)      < nAtoms;
        const bool v1 = (base + 32 + lm) < nAtoms;
        float e0 = 0.f, e1 = 0.f;
        #pragma unroll
        for (int r = 0; r < 16; ++r) {
            const int f = Fw + (r & 3) + 8 * (r >> 2) + 4 * hi;
            const float h3a = silu(acc0[r]);
            const float h3b = silu(acc1[r]);
            const float we = WeL[f];
            e0 = fmaf(h3a, we, e0);
            e1 = fmaf(h3b, we, e1);
            const float hs = (v0 ? h3a : 0.f) + (v1 ? h3b : 0.f);
            #pragma unroll
            for (int c = 0; c < 6; ++c) sacc[c] = fmaf(hs, WsL[f][c], sacc[c]);
        }
        // combine lane halves: each lane then holds full e for its atom column
        e0 += __shfl_xor(e0, 32);
        e1 += __shfl_xor(e1, 32);
        const float ev = (lane < 32) ? e0 : e1;   // lane l <-> atom base+l
        ered[w * 64 + lane] = ev;
        __syncthreads();

        // ---- wave 0: sum feature slices, add b_e, segmented-scan, atomic ----
        if (w == 0) {
            float e = ered[lane] + ered[64 + lane] + ered[128 + lane] + ered[192 + lane] + be;
            const int ga = base + lane;
            int key = (ga < nAtoms) ? batch[ga] : -1;
            if (key < 0) e = 0.f;
            #pragma unroll
            for (int d = 1; d < 64; d <<= 1) {
                const float eo = __shfl_down(e, d);
                const int   ko = __shfl_down(key, d);
                const bool valid = ((lane + d) < 64) && (ko == key);
                e += valid ? eo : 0.f;
            }
            const int kprev = __shfl_up(key, 1);
            const bool head = (lane == 0) || (kprev != key);
            if (head && key >= 0) atomicAdd(&out_energies[key], e);
        }
    }

    // ---- stress: reduce 6 per-lane partials across wave, one atomic each ----
    #pragma unroll
    for (int c = 0; c < 6; ++c) {
        float v = sacc[c];
        #pragma unroll
        for (int d = 1; d < 64; d <<= 1) v += __shfl_xor(v, d);
        if (lane == 0) atomicAdd(&ws6[c], v);
    }
}

__global__ void stress_kernel(const float* __restrict__ ws6,
                              const float* __restrict__ b_s,
                              float* __restrict__ out_stress, float invN)
{
    const int c = threadIdx.x;
    if (c < 6) out_stress[c] = fmaf(ws6[c], invN, b_s[c]);
}

extern "C" void kernel_launch(void* const* d_in, const int* in_sizes, int n_in,
                              void* d_out, int out_size, void* d_ws, size_t ws_size,
                              hipStream_t stream) {
    const float* pos  = (const float*)d_in[0];
    const int*   anum = (const int*)d_in[1];
    const int*   batch= (const int*)d_in[2];
    const float* W_in = (const float*)d_in[3];
    const float* b_in = (const float*)d_in[4];
    const float* W_h  = (const float*)d_in[5];
    const float* b_h  = (const float*)d_in[6];
    const float* W_e  = (const float*)d_in[7];
    const float* b_e  = (const float*)d_in[8];
    const float* W_s  = (const float*)d_in[9];
    const float* b_s  = (const float*)d_in[10];

    float* out = (float*)d_out;
    const int nAtoms  = in_sizes[2];                 // batch[] length == N
    const int nStruct = out_size - 3 * nAtoms - 6;   // energies | forces | stress
    float* ws6 = (float*)d_ws;

    hipMemsetAsync(d_out, 0, (size_t)out_size * sizeof(float), stream);
    hipMemsetAsync(d_ws, 0, 32, stream);

    mlp_kernel<<<NBLOCKS, TPB, 0, stream>>>(pos, anum, batch, W_in, b_in, W_h, b_h,
                                            W_e, b_e, W_s, out, ws6, nAtoms);
    stress_kernel<<<1, 64, 0, stream>>>(ws6, b_s,
                                        out + (size_t)nStruct + 3 * (size_t)nAtoms,
                                        1.0f / (float)nAtoms);
}